// Round 10
// baseline (476.383 us; speedup 1.0000x reference)
//
#include <hip/hip_runtime.h>
#include <hip/hip_bf16.h>
#include <stdint.h>

#define M_DIM 4096
#define K_DIM 4096
#define N_DIM 11008
#define BKT 64                 // K per tile
#define NT (K_DIM / BKT)       // 64 k-tiles
#define GRID_MN 688            // (4096/256) * (11008/256) = 16*43
#define NBLK_M 16

typedef __attribute__((ext_vector_type(8))) short short8;
typedef __attribute__((ext_vector_type(4))) float floatx4;

#define MFMA16 __builtin_amdgcn_mfma_f32_16x16x32_bf16

// f32 -> bf16 round-to-nearest-even
__device__ __forceinline__ short f2bf(float f) {
  union { float f; uint32_t u; } c; c.f = f;
  uint32_t u = c.u;
  u += 0x7FFFu + ((u >> 16) & 1u);
  return (short)(u >> 16);
}

__device__ __forceinline__ void gload_lds16(const void* g, void* l) {
  __builtin_amdgcn_global_load_lds(
      (const __attribute__((address_space(1))) unsigned int*)g,
      (__attribute__((address_space(3))) unsigned int*)l, 16, 0, 0);
}

// ---------------- x: f32 -> bf16, plus exact f32 row sums ----------------
__global__ __launch_bounds__(256) void convert_x_kernel(const float* __restrict__ x,
                                                        short* __restrict__ xb,
                                                        float* __restrict__ rowsum) {
  const int m = blockIdx.x;
  const int t = threadIdx.x;
  const float* row = x + (size_t)m * K_DIM + t * 16;
  short* orow = xb + (size_t)m * K_DIM + t * 16;
  float4 v0 = *(const float4*)(row + 0);
  float4 v1 = *(const float4*)(row + 4);
  float4 v2 = *(const float4*)(row + 8);
  float4 v3 = *(const float4*)(row + 12);
  float sum = v0.x + v0.y + v0.z + v0.w
            + v1.x + v1.y + v1.z + v1.w
            + v2.x + v2.y + v2.z + v2.w
            + v3.x + v3.y + v3.z + v3.w;
  short8 o0, o1;
  o0[0] = f2bf(v0.x); o0[1] = f2bf(v0.y); o0[2] = f2bf(v0.z); o0[3] = f2bf(v0.w);
  o0[4] = f2bf(v1.x); o0[5] = f2bf(v1.y); o0[6] = f2bf(v1.z); o0[7] = f2bf(v1.w);
  o1[0] = f2bf(v2.x); o1[1] = f2bf(v2.y); o1[2] = f2bf(v2.z); o1[3] = f2bf(v2.w);
  o1[4] = f2bf(v3.x); o1[5] = f2bf(v3.y); o1[6] = f2bf(v3.z); o1[7] = f2bf(v3.w);
  *(short8*)(orow) = o0;
  *(short8*)(orow + 8) = o1;
  #pragma unroll
  for (int off = 32; off > 0; off >>= 1) sum += __shfl_down(sum, off);
  __shared__ float part[4];
  if ((t & 63) == 0) part[t >> 6] = sum;
  __syncthreads();
  if (t == 0) rowsum[m] = part[0] + part[1] + part[2] + part[3];
}

// ---------------- w: int32 [K][N] -> bf16 MFMA-fragment-blocked wt2 ----------------
// wt2 layout: block (nt = n>>4, ktN = k>>5) of 512 shorts:
//   wt2[((nt*128 + ktN)*64 + lane)*8 + j] = bf16(w[k][n])
//   with n = nt*16 + (lane&15), k = ktN*32 + (lane>>4)*8 + j.
// A wave's B-fragment load = global_load_dwordx4 at block_base + lane*16B (coalesced 1KB).
__global__ __launch_bounds__(256) void convert_w_kernel(const int* __restrict__ w,
                                                        short* __restrict__ wt2) {
  __shared__ short tile[64][72];
  const int bk = blockIdx.x * 64;
  const int bn = blockIdx.y * 64;
  const int t = threadIdx.x;
  const int kr = t >> 2;
  const int c0 = (t & 3) * 16;
  const int* src = w + (size_t)(bk + kr) * N_DIM + bn + c0;
  int4 a = *(const int4*)(src + 0);
  int4 b = *(const int4*)(src + 4);
  int4 c = *(const int4*)(src + 8);
  int4 d = *(const int4*)(src + 12);
  short* dst = &tile[kr][c0];
  dst[0]  = f2bf((float)a.x); dst[1]  = f2bf((float)a.y);
  dst[2]  = f2bf((float)a.z); dst[3]  = f2bf((float)a.w);
  dst[4]  = f2bf((float)b.x); dst[5]  = f2bf((float)b.y);
  dst[6]  = f2bf((float)b.z); dst[7]  = f2bf((float)b.w);
  dst[8]  = f2bf((float)c.x); dst[9]  = f2bf((float)c.y);
  dst[10] = f2bf((float)c.z); dst[11] = f2bf((float)c.w);
  dst[12] = f2bf((float)d.x); dst[13] = f2bf((float)d.y);
  dst[14] = f2bf((float)d.z); dst[15] = f2bf((float)d.w);
  __syncthreads();
  // write phase: 8 blocks (nt_l 0..3 x ktN_l 0..1); thread covers lanes 2(t&31), +1
  const int blk = t >> 5;
  const int ktN_l = blk & 1;
  const int nt_l = blk >> 1;
  short8 o0, o1;
  {
    const int l = (t & 31) * 2;
    const int nl = nt_l * 16 + (l & 15);
    const int kb = ktN_l * 32 + (l >> 4) * 8;
    #pragma unroll
    for (int j = 0; j < 8; ++j) o0[j] = tile[kb + j][nl];
  }
  {
    const int l = (t & 31) * 2 + 1;
    const int nl = nt_l * 16 + (l & 15);
    const int kb = ktN_l * 32 + (l >> 4) * 8;
    #pragma unroll
    for (int j = 0; j < 8; ++j) o1[j] = tile[kb + j][nl];
  }
  const size_t nt_g = (size_t)(bn >> 4) + nt_l;
  const size_t ktN_g = (size_t)(bk >> 5) + ktN_l;
  short* od = wt2 + (nt_g * 128 + ktN_g) * 512 + (size_t)((t & 31) * 2) * 8;
  *(short8*)(od) = o0;
  *(short8*)(od + 8) = o1;
}

// ---------------- main GEMM: 256x256 tile, 8 waves, A-in-LDS + B-direct-to-reg ----------------
// LDS: A only, lds[buf][half: 0 = rows 0-127, 1 = rows 128-255][8192] (64KB).
// Swizzle (A only): 16B granule g of row stored at g ^ (row & 7).
// Step u (buf G=u&1), ONE barrier/step. vm-FIFO/step: P1 A1stage[2], P2 b0'[4],
// P4 A0stage[2]+b1'[4]. Steady waits: P1 vmcnt(6) {retire b0(u)}, P3 vmcnt(6)
// {retire A0(u+1)+b1(u)}, P4 vmcnt(4) {retire A1(u+1)} + s_barrier.
//   P1: lgkm(0){a03}; vmcnt(6); ds_read a47(u); stage A1(u+1)->GN; Q00=a03*b0
//   P2: lgkm(0){a47}; Q10=a47*b0; load b0(u+1)
//   P3: vmcnt(6); Q11=a47*b1
//   P4: vmcnt(4); BARRIER; stage A0(u+2)->G; Q01=a03*b1; load b1(u+1);
//       ds_read a03(u+1) from GN
// WAR safety (chip-wide, vs the single P4 barrier): every LDS region's stage
// issues only after a barrier that follows all waves' lgkm-retirement of that
// region's reads (verified per region). RAW: stages retired by counted vmcnt
// pre-barrier, reads issue post-barrier.
__global__ __launch_bounds__(512, 2) void gemm_kernel(const short* __restrict__ xb,
                                                      const short* __restrict__ wt2,
                                                      const float* __restrict__ scale,
                                                      const float* __restrict__ offset,
                                                      const float* __restrict__ rowsum,
                                                      float* __restrict__ out) {
  __shared__ short lds[2][2][8192];
  const int tid = threadIdx.x;
  // bijective XCD swizzle: 688 = 8 * 86; n-major so each XCD owns an N-slice
  const int bid = blockIdx.x;
  const int wg = (bid & 7) * (GRID_MN / 8) + (bid >> 3);
  const int bm = (wg % NBLK_M) * 256;
  const int bn = (wg / NBLK_M) * 256;

  const int wid = tid >> 6;
  const int lane = tid & 63;
  const int wr = wid >> 2;              // 0..1 : M half
  const int wc = wid & 3;               // 0..3 : N quarter
  const int lr = lane & 15;
  const int lg = lane >> 4;
  const int swz = lr & 7;
  const int gk0 = (lg ^ swz) * 8;       // k-half 0 granule (shorts)
  const int gk1 = ((lg ^ 4) ^ swz) * 8; // k-half 1 granule (shorts)

  // A staging: thread covers 16B slots tid and tid+512 of a 16KB half-tile
  const int srow = tid >> 3;
  const int glog = (tid & 7) ^ (srow & 7);
  const size_t toff = (size_t)srow * K_DIM + glog * 8;
  const short* pA0 = xb + (size_t)bm * K_DIM + toff;
  const short* pA1 = xb + ((size_t)bm + 128) * K_DIM + toff;

  auto stage2 = [&](const short* p, short* region) {
    gload_lds16(p, (char*)region + tid * 16);
    gload_lds16(p + (size_t)64 * K_DIM, (char*)region + (tid + 512) * 16);
  };

  // B fragment pointers (blocked wt2): frag f covers n = bn + wc*64 + f*16 + lr
  const int ntb = (bn >> 4) + wc * 4;
  const short* bp0 = wt2 + (size_t)(ntb + 0) * 65536 + (size_t)lane * 8;
  const short* bp1 = wt2 + (size_t)(ntb + 1) * 65536 + (size_t)lane * 8;
  const short* bp2 = wt2 + (size_t)(ntb + 2) * 65536 + (size_t)lane * 8;
  const short* bp3 = wt2 + (size_t)(ntb + 3) * 65536 + (size_t)lane * 8;

  floatx4 acc[8][4];
  const floatx4 zero = {0.f, 0.f, 0.f, 0.f};
  #pragma unroll
  for (int i = 0; i < 8; ++i)
    #pragma unroll
    for (int j = 0; j < 4; ++j) acc[i][j] = zero;

  short8 a03[4][2], a47[4][2], b0[2][2], b1[2][2];

  // ---- prologue: FIFO = A0(0)2, A1(0)2, b0(0)4, A0(1)2, b1(0)4 ----
  stage2(pA0, &lds[0][0][0]);
  stage2(pA1, &lds[0][1][0]);
  b0[0][0] = *(const short8*)(bp0); b0[0][1] = *(const short8*)(bp0 + 512);
  b0[1][0] = *(const short8*)(bp1); b0[1][1] = *(const short8*)(bp1 + 512);
  stage2(pA0 + BKT, &lds[1][0][0]);
  b1[0][0] = *(const short8*)(bp2); b1[0][1] = *(const short8*)(bp2 + 512);
  b1[1][0] = *(const short8*)(bp3); b1[1][1] = *(const short8*)(bp3 + 512);
  bp0 += 1024; bp1 += 1024; bp2 += 1024; bp3 += 1024;
  pA0 += 2 * BKT;
  pA1 += BKT;
  asm volatile("s_waitcnt vmcnt(10)" ::: "memory");  // A0(0), A1(0) resident
  __builtin_amdgcn_s_barrier();

  const short* const AsB[2] = {&lds[0][wr][0], &lds[1][wr][0]};
  {
    const short* As = AsB[0];
    #pragma unroll
    for (int mf = 0; mf < 4; ++mf) {
      const short* p = As + (mf * 16 + lr) * 64;
      a03[mf][0] = *(const short8*)(p + gk0);
      a03[mf][1] = *(const short8*)(p + gk1);
    }
  }

#define STEP(G, GN, A0STG, TAILF)                                              \
  {                                                                            \
    const short* As = AsB[G];                                                  \
    /* ---- P1 ---- */                                                         \
    asm volatile("s_waitcnt lgkmcnt(0)" ::: "memory");                         \
    if (TAILF) { asm volatile("s_waitcnt vmcnt(4)" ::: "memory"); }            \
    else       { asm volatile("s_waitcnt vmcnt(6)" ::: "memory"); }            \
    __builtin_amdgcn_sched_barrier(0);                                         \
    _Pragma("unroll")                                                          \
    for (int mf = 0; mf < 4; ++mf) {                                           \
      const short* p = As + ((mf + 4) * 16 + lr) * 64;                         \
      a47[mf][0] = *(const short8*)(p + gk0);                                  \
      a47[mf][1] = *(const short8*)(p + gk1);                                  \
    }                                                                          \
    if (!TAILF) { stage2(pA1, &lds[GN][1][0]); pA1 += BKT; }                   \
    __builtin_amdgcn_s_setprio(1);                                             \
    _Pragma("unroll")                                                          \
    for (int mf = 0; mf < 4; ++mf)                                             \
      _Pragma("unroll")                                                        \
      for (int nf = 0; nf < 2; ++nf) {                                         \
        acc[mf][nf] = MFMA16(a03[mf][0], b0[nf][0], acc[mf][nf], 0, 0, 0);     \
        acc[mf][nf] = MFMA16(a03[mf][1], b0[nf][1], acc[mf][nf], 0, 0, 0);     \
      }                                                                        \
    __builtin_amdgcn_s_setprio(0);                                             \
    /* ---- P2 ---- */                                                         \
    asm volatile("s_waitcnt lgkmcnt(0)" ::: "memory");                         \
    __builtin_amdgcn_sched_barrier(0);                                         \
    __builtin_amdgcn_s_setprio(1);                                             \
    _Pragma("unroll")                                                          \
    for (int mf = 0; mf < 4; ++mf)                                             \
      _Pragma("unroll")                                                        \
      for (int nf = 0; nf < 2; ++nf) {                                         \
        acc[mf + 4][nf] = MFMA16(a47[mf][0], b0[nf][0], acc[mf + 4][nf], 0, 0, 0); \
        acc[mf + 4][nf] = MFMA16(a47[mf][1], b0[nf][1], acc[mf + 4][nf], 0, 0, 0); \
      }                                                                        \
    __builtin_amdgcn_s_setprio(0);                                             \
    if (!TAILF) {                                                              \
      b0[0][0] = *(const short8*)(bp0); b0[0][1] = *(const short8*)(bp0 + 512);\
      b0[1][0] = *(const short8*)(bp1); b0[1][1] = *(const short8*)(bp1 + 512);\
    }                                                                          \
    /* ---- P3 ---- */                                                         \
    if (TAILF) { asm volatile("s_waitcnt vmcnt(0)" ::: "memory"); }            \
    else       { asm volatile("s_waitcnt vmcnt(6)" ::: "memory"); }            \
    __builtin_amdgcn_sched_barrier(0);                                         \
    __builtin_amdgcn_s_setprio(1);                                             \
    _Pragma("unroll")                                                          \
    for (int mf = 0; mf < 4; ++mf)                                             \
      _Pragma("unroll")                                                        \
      for (int nf = 0; nf < 2; ++nf) {                                         \
        acc[mf + 4][nf + 2] = MFMA16(a47[mf][0], b1[nf][0], acc[mf + 4][nf + 2], 0, 0, 0); \
        acc[mf + 4][nf + 2] = MFMA16(a47[mf][1], b1[nf][1], acc[mf + 4][nf + 2], 0, 0, 0); \
      }                                                                        \
    __builtin_amdgcn_s_setprio(0);                                             \
    /* ---- P4 ---- */                                                         \
    if (TAILF) { asm volatile("s_waitcnt vmcnt(0)" ::: "memory"); }            \
    else       { asm volatile("s_waitcnt vmcnt(4)" ::: "memory"); }            \
    if (!TAILF) __builtin_amdgcn_s_barrier();                                  \
    if (A0STG) { stage2(pA0, &lds[G][0][0]); pA0 += BKT; }                     \
    __builtin_amdgcn_s_setprio(1);                                             \
    _Pragma("unroll")                                                          \
    for (int mf = 0; mf < 4; ++mf)                                             \
      _Pragma("unroll")                                                        \
      for (int nf = 0; nf < 2; ++nf) {                                         \
        acc[mf][nf + 2] = MFMA16(a03[mf][0], b1[nf][0], acc[mf][nf + 2], 0, 0, 0); \
        acc[mf][nf + 2] = MFMA16(a03[mf][1], b1[nf][1], acc[mf][nf + 2], 0, 0, 0); \
      }                                                                        \
    __builtin_amdgcn_s_setprio(0);                                             \
    if (!TAILF) {                                                              \
      b1[0][0] = *(const short8*)(bp2); b1[0][1] = *(const short8*)(bp2 + 512);\
      b1[1][0] = *(const short8*)(bp3); b1[1][1] = *(const short8*)(bp3 + 512);\
      bp0 += 1024; bp1 += 1024; bp2 += 1024; bp3 += 1024;                      \
      const short* An = AsB[GN];                                               \
      _Pragma("unroll")                                                        \
      for (int mf = 0; mf < 4; ++mf) {                                         \
        const short* p = An + (mf * 16 + lr) * 64;                             \
        a03[mf][0] = *(const short8*)(p + gk0);                                \
        a03[mf][1] = *(const short8*)(p + gk1);                                \
      }                                                                        \
    }                                                                          \
  }

  // steady steps 0..61, then u=62 (no A0(64) stage), then u=63 (tail)
  for (int u = 0; u < NT - 2; u += 2) {
    STEP(0, 1, 1, 0)
    STEP(1, 0, 1, 0)
  }
  STEP(0, 1, 0, 0)
  STEP(1, 0, 0, 1)
#undef STEP

  // ---- epilogue: out = (G + offset[n]*rowsum[m]) * scale[n] ----
  const int orow0 = bm + wr * 128 + lg * 4;
  const int ocol0 = bn + wc * 64 + lr;
  float4 rsv[8];
  #pragma unroll
  for (int amf = 0; amf < 8; ++amf)
    rsv[amf] = *(const float4*)&rowsum[orow0 + amf * 16];
  #pragma unroll
  for (int anf = 0; anf < 4; ++anf) {
    const int n = ocol0 + anf * 16;
    const float sc = scale[n];
    const float of = offset[n];
    #pragma unroll
    for (int amf = 0; amf < 8; ++amf) {
      const int mbase = orow0 + amf * 16;
      const float4 rv = rsv[amf];
      out[(size_t)(mbase + 0) * N_DIM + n] = (acc[amf][anf][0] + of * rv.x) * sc;
      out[(size_t)(mbase + 1) * N_DIM + n] = (acc[amf][anf][1] + of * rv.y) * sc;
      out[(size_t)(mbase + 2) * N_DIM + n] = (acc[amf][anf][2] + of * rv.z) * sc;
      out[(size_t)(mbase + 3) * N_DIM + n] = (acc[amf][anf][3] + of * rv.w) * sc;
    }
  }
}

// ---------------- fallback (ws too small): exact f32 tiled GEMM ----------------
__global__ __launch_bounds__(256) void fallback_gemm(const float* __restrict__ x,
                                                     const int* __restrict__ w,
                                                     const float* __restrict__ scale,
                                                     const float* __restrict__ offset,
                                                     float* __restrict__ out) {
  __shared__ float xs[32][33];
  __shared__ float bs[32][33];
  const int bm = blockIdx.y * 32, bn = blockIdx.x * 32;
  const int t = threadIdx.x;
  const int tm = t >> 5, tn = t & 31;
  float acc[4] = {0.f, 0.f, 0.f, 0.f};
  for (int k0 = 0; k0 < K_DIM; k0 += 32) {
    #pragma unroll
    for (int i = 0; i < 4; ++i) {
      int idx = t + i * 256; int r = idx >> 5, c = idx & 31;
      xs[r][c] = x[(size_t)(bm + r) * K_DIM + k0 + c];
      bs[r][c] = ((float)w[(size_t)(k0 + r) * N_DIM + bn + c] + offset[bn + c]) * scale[bn + c];
    }
    __syncthreads();
    #pragma unroll 8
    for (int kk = 0; kk < 32; ++kk) {
      float wv = bs[kk][tn];
      #pragma unroll
      for (int i = 0; i < 4; ++i) acc[i] += xs[tm + 8 * i][kk] * wv;
    }
    __syncthreads();
  }
  #pragma unroll
  for (int i = 0; i < 4; ++i)
    out[(size_t)(bm + tm + 8 * i) * N_DIM + bn + tn] = acc[i];
}

extern "C" void kernel_launch(void* const* d_in, const int* in_sizes, int n_in,
                              void* d_out, int out_size, void* d_ws, size_t ws_size,
                              hipStream_t stream) {
  const float* x      = (const float*)d_in[0];
  const int*   w      = (const int*)d_in[1];
  const float* scale  = (const float*)d_in[2];
  const float* offset = (const float*)d_in[3];
  float* out = (float*)d_out;

  const size_t xb_bytes = (size_t)M_DIM * K_DIM * 2;
  const size_t wt_bytes = (size_t)N_DIM * K_DIM * 2;
  const size_t rs_bytes = (size_t)M_DIM * 4;

  if (ws_size >= xb_bytes + wt_bytes + rs_bytes) {
    short* xb = (short*)d_ws;
    short* wt2 = (short*)((char*)d_ws + xb_bytes);
    float* rowsum = (float*)((char*)d_ws + xb_bytes + wt_bytes);
    convert_x_kernel<<<M_DIM, 256, 0, stream>>>(x, xb, rowsum);
    convert_w_kernel<<<dim3(K_DIM / 64, N_DIM / 64), 256, 0, stream>>>(w, wt2);
    gemm_kernel<<<GRID_MN, 512, 0, stream>>>(xb, wt2, scale, offset, rowsum, out);
  } else {
    fallback_gemm<<<dim3(N_DIM / 32, M_DIM / 32), 256, 0, stream>>>(x, w, scale, offset, out);
  }
}

// Round 11
// 443.266 us; speedup vs baseline: 1.0747x; 1.0747x over previous
//
#include <hip/hip_runtime.h>
#include <hip/hip_bf16.h>
#include <stdint.h>

#define M_DIM 4096
#define K_DIM 4096
#define N_DIM 11008
#define BKT 64                 // K per tile
#define NT (K_DIM / BKT)       // 64 k-tiles
#define GRID_MN 688            // (4096/256) * (11008/256) = 16*43
#define NBLK_M 16

typedef __attribute__((ext_vector_type(8))) short short8;
typedef __attribute__((ext_vector_type(16))) float floatx16;

#define MFMA32 __builtin_amdgcn_mfma_f32_32x32x16_bf16

// f32 -> bf16 round-to-nearest-even
__device__ __forceinline__ short f2bf(float f) {
  union { float f; uint32_t u; } c; c.f = f;
  uint32_t u = c.u;
  u += 0x7FFFu + ((u >> 16) & 1u);
  return (short)(u >> 16);
}

__device__ __forceinline__ void gload_lds16(const void* g, void* l) {
  __builtin_amdgcn_global_load_lds(
      (const __attribute__((address_space(1))) unsigned int*)g,
      (__attribute__((address_space(3))) unsigned int*)l, 16, 0, 0);
}

// ---------------- x: f32 -> bf16, plus exact f32 row sums ----------------
__global__ __launch_bounds__(256) void convert_x_kernel(const float* __restrict__ x,
                                                        short* __restrict__ xb,
                                                        float* __restrict__ rowsum) {
  const int m = blockIdx.x;
  const int t = threadIdx.x;
  const float* row = x + (size_t)m * K_DIM + t * 16;
  short* orow = xb + (size_t)m * K_DIM + t * 16;
  float4 v0 = *(const float4*)(row + 0);
  float4 v1 = *(const float4*)(row + 4);
  float4 v2 = *(const float4*)(row + 8);
  float4 v3 = *(const float4*)(row + 12);
  float sum = v0.x + v0.y + v0.z + v0.w
            + v1.x + v1.y + v1.z + v1.w
            + v2.x + v2.y + v2.z + v2.w
            + v3.x + v3.y + v3.z + v3.w;
  short8 o0, o1;
  o0[0] = f2bf(v0.x); o0[1] = f2bf(v0.y); o0[2] = f2bf(v0.z); o0[3] = f2bf(v0.w);
  o0[4] = f2bf(v1.x); o0[5] = f2bf(v1.y); o0[6] = f2bf(v1.z); o0[7] = f2bf(v1.w);
  o1[0] = f2bf(v2.x); o1[1] = f2bf(v2.y); o1[2] = f2bf(v2.z); o1[3] = f2bf(v2.w);
  o1[4] = f2bf(v3.x); o1[5] = f2bf(v3.y); o1[6] = f2bf(v3.z); o1[7] = f2bf(v3.w);
  *(short8*)(orow) = o0;
  *(short8*)(orow + 8) = o1;
  #pragma unroll
  for (int off = 32; off > 0; off >>= 1) sum += __shfl_down(sum, off);
  __shared__ float part[4];
  if ((t & 63) == 0) part[t >> 6] = sum;
  __syncthreads();
  if (t == 0) rowsum[m] = part[0] + part[1] + part[2] + part[3];
}

// ---------------- w: int32 [K][N] -> bf16 transposed [N][K] ----------------
__global__ __launch_bounds__(256) void convert_w_kernel(const int* __restrict__ w,
                                                        short* __restrict__ wt) {
  __shared__ short tile[64][72];
  const int bk = blockIdx.x * 64;
  const int bn = blockIdx.y * 64;
  const int t = threadIdx.x;
  const int kr = t >> 2;
  const int c0 = (t & 3) * 16;
  const int* src = w + (size_t)(bk + kr) * N_DIM + bn + c0;
  int4 a = *(const int4*)(src + 0);
  int4 b = *(const int4*)(src + 4);
  int4 c = *(const int4*)(src + 8);
  int4 d = *(const int4*)(src + 12);
  short* dst = &tile[kr][c0];
  dst[0]  = f2bf((float)a.x); dst[1]  = f2bf((float)a.y);
  dst[2]  = f2bf((float)a.z); dst[3]  = f2bf((float)a.w);
  dst[4]  = f2bf((float)b.x); dst[5]  = f2bf((float)b.y);
  dst[6]  = f2bf((float)b.z); dst[7]  = f2bf((float)b.w);
  dst[8]  = f2bf((float)c.x); dst[9]  = f2bf((float)c.y);
  dst[10] = f2bf((float)c.z); dst[11] = f2bf((float)c.w);
  dst[12] = f2bf((float)d.x); dst[13] = f2bf((float)d.y);
  dst[14] = f2bf((float)d.z); dst[15] = f2bf((float)d.w);
  __syncthreads();
  const int nr = t >> 2;
  short8 o0, o1;
  #pragma unroll
  for (int j = 0; j < 8; ++j) o0[j] = tile[c0 + j][nr];
  #pragma unroll
  for (int j = 0; j < 8; ++j) o1[j] = tile[c0 + 8 + j][nr];
  short* odst = wt + (size_t)(bn + nr) * K_DIM + bk + c0;
  *(short8*)(odst) = o0;
  *(short8*)(odst + 8) = o1;
}

// ---------------- main GEMM: 256x256 tile, 8 waves, R9 schedule + 32x32x16 MFMA ----------------
// LDS: [buf][region: 0=A0,1=A1,2=B0,3=B1][128 rows x 64 k], swizzle granule ^= row&7.
// Fragments (mfma_f32_32x32x16_bf16, m74/m101-verified layouts):
//   A/B: lane holds row/col = lane&31, k = (lane>>5)*8 + j  (one 16B read per frag)
//   C/D: col = lane&31, row = (reg&3) + 8*(reg>>2) + 4*(lane>>5)
// Wave tile 128x64 = a-frags mf 0..3 (32 rows each) x b-frags nf 0..1 (32 cols) x 4 k-slices.
// Schedule per step u (buf G=u&1), IDENTICAL to R9/R7 (346us verified ledger):
//   P1: read a23 [8]; lgkm(8); BAR; stage A1(u+1)->GN; Q00 = a01 x b0
//   P2: read b1 [4];  lgkm(4); BAR; stage A0(u+2)->G;  Q10 = a23 x b0
//   P3:               lgkm(0); BAR; stage B0(u+2)->G;  Q01 = a01 x b1
//   P4: stage B1(u+2)->G; vmcnt(6){retires tile u+1}; BAR;
//       refill a01,b0(u+1) from GN [12]; Q11 = a23 x b1
__global__ __launch_bounds__(512, 2) void gemm_kernel(const short* __restrict__ xb,
                                                      const short* __restrict__ wt,
                                                      const float* __restrict__ scale,
                                                      const float* __restrict__ offset,
                                                      const float* __restrict__ rowsum,
                                                      float* __restrict__ out) {
  __shared__ short lds[2][4][8192];
  const int tid = threadIdx.x;
  // bijective XCD swizzle: 688 = 8 * 86; n-major so each XCD owns an N-slice
  const int bid = blockIdx.x;
  const int wg = (bid & 7) * (GRID_MN / 8) + (bid >> 3);
  const int bm = (wg % NBLK_M) * 256;
  const int bn = (wg / NBLK_M) * 256;

  const int wid = tid >> 6;
  const int lane = tid & 63;
  const int wr = wid >> 2;              // 0..1 : M half
  const int wc = wid & 3;               // 0..3 : N quarter
  const int hb = wc >> 1;               // which B half-region
  const int l31 = lane & 31;
  const int hi = lane >> 5;
  const int swz = lane & 7;             // = row & 7 for every row this lane touches
  // granule offset (shorts) for k-slice ks: ((2ks|hi)^swz)*8
  const int goff0 = (((0) | hi) ^ swz) * 8;
  const int goff1 = (((2) | hi) ^ swz) * 8;
  const int goff2 = (((4) | hi) ^ swz) * 8;
  const int goff3 = (((6) | hi) ^ swz) * 8;
  const int gof[4] = {goff0, goff1, goff2, goff3};
  const int brow0 = (wc & 1) * 64 + l31;        // b0 rows in region
  const int brow1 = (wc & 1) * 64 + 32 + l31;   // b1 rows

  // A staging: thread covers 16B slots tid and tid+512 of a 16KB half-tile
  const int srow = tid >> 3;
  const int glog = (tid & 7) ^ (srow & 7);
  const size_t toff = (size_t)srow * K_DIM + glog * 8;
  const short* pA0 = xb + (size_t)bm * K_DIM + toff;
  const short* pA1 = xb + ((size_t)bm + 128) * K_DIM + toff;
  const short* pB0 = wt + (size_t)bn * K_DIM + toff;
  const short* pB1 = wt + ((size_t)bn + 128) * K_DIM + toff;

  auto stage2 = [&](const short* p, short* region) {
    gload_lds16(p, (char*)region + tid * 16);
    gload_lds16(p + (size_t)64 * K_DIM, (char*)region + (tid + 512) * 16);
  };

  floatx16 acc[4][2];
  #pragma unroll
  for (int i = 0; i < 4; ++i)
    #pragma unroll
    for (int j = 0; j < 2; ++j)
      #pragma unroll
      for (int r = 0; r < 16; ++r) acc[i][j][r] = 0.f;

  // ---- prologue: FIFO = A0(0),A1(0),B0(0),B1(0),B0(1),A0(1),B1(1) = 14 loads ----
  stage2(pA0, &lds[0][0][0]);
  stage2(pA1, &lds[0][1][0]);
  stage2(pB0, &lds[0][2][0]);
  stage2(pB1, &lds[0][3][0]);
  stage2(pB0 + BKT, &lds[1][2][0]);
  stage2(pA0 + BKT, &lds[1][0][0]);
  stage2(pB1 + BKT, &lds[1][3][0]);
  asm volatile("s_waitcnt vmcnt(6)" ::: "memory");  // tile0 landed
  __builtin_amdgcn_s_barrier();
  pA1 += BKT;
  pA0 += 2 * BKT;
  pB0 += 2 * BKT;
  pB1 += 2 * BKT;

  const short* const AsB[2] = {&lds[0][wr][0], &lds[1][wr][0]};
  const short* const BsB[2] = {&lds[0][2 + hb][0], &lds[1][2 + hb][0]};

  short8 a01[2][4], a23[2][4], b0v[4], b1v[4];
  {
    // read a01(0) [8] + b0(0) [4]: 12 lgkm outstanding entering the loop
    const short* As = AsB[0];
    #pragma unroll
    for (int mf = 0; mf < 2; ++mf)
      #pragma unroll
      for (int ks = 0; ks < 4; ++ks)
        a01[mf][ks] = *(const short8*)(As + (mf * 32 + l31) * 64 + gof[ks]);
    const short* Bs = BsB[0];
    #pragma unroll
    for (int ks = 0; ks < 4; ++ks)
      b0v[ks] = *(const short8*)(Bs + brow0 * 64 + gof[ks]);
  }

#define STEP_BODY(G, GN)                                                       \
  {                                                                            \
    const short* As = AsB[G];                                                  \
    const short* Bs = BsB[G];                                                  \
    /* P1: read a23(u) [8]; lgkm(8); BAR; stage A1(u+1)->GN; Q00 */            \
    _Pragma("unroll")                                                          \
    for (int mf = 0; mf < 2; ++mf)                                             \
      _Pragma("unroll")                                                        \
      for (int ks = 0; ks < 4; ++ks)                                           \
        a23[mf][ks] = *(const short8*)(As + ((mf + 2) * 32 + l31) * 64 + gof[ks]); \
    asm volatile("s_waitcnt lgkmcnt(8)" ::: "memory");                         \
    __builtin_amdgcn_s_barrier();                                              \
    if (u + 1 < NT) stage2(pA1, &lds[GN][1][0]);                               \
    pA1 += BKT;                                                                \
    __builtin_amdgcn_s_setprio(1);                                             \
    _Pragma("unroll")                                                          \
    for (int mf = 0; mf < 2; ++mf)                                             \
      _Pragma("unroll")                                                        \
      for (int ks = 0; ks < 4; ++ks)                                           \
        acc[mf][0] = MFMA32(a01[mf][ks], b0v[ks], acc[mf][0], 0, 0, 0);        \
    __builtin_amdgcn_s_setprio(0);                                             \
    /* P2: read b1(u) [4]; lgkm(4); BAR; stage A0(u+2)->G; Q10 */              \
    _Pragma("unroll")                                                          \
    for (int ks = 0; ks < 4; ++ks)                                             \
      b1v[ks] = *(const short8*)(Bs + brow1 * 64 + gof[ks]);                   \
    asm volatile("s_waitcnt lgkmcnt(4)" ::: "memory");                         \
    __builtin_amdgcn_s_barrier();                                              \
    if (u + 2 < NT) stage2(pA0, &lds[G][0][0]);                                \
    pA0 += BKT;                                                                \
    __builtin_amdgcn_s_setprio(1);                                             \
    _Pragma("unroll")                                                          \
    for (int mf = 0; mf < 2; ++mf)                                             \
      _Pragma("unroll")                                                        \
      for (int ks = 0; ks < 4; ++ks)                                           \
        acc[mf + 2][0] = MFMA32(a23[mf][ks], b0v[ks], acc[mf + 2][0], 0, 0, 0);\
    __builtin_amdgcn_s_setprio(0);                                             \
    /* P3: lgkm(0); BAR; stage B0(u+2)->G; Q01 */                              \
    asm volatile("s_waitcnt lgkmcnt(0)" ::: "memory");                         \
    __builtin_amdgcn_s_barrier();                                              \
    if (u + 2 < NT) stage2(pB0, &lds[G][2][0]);                                \
    pB0 += BKT;                                                                \
    __builtin_amdgcn_s_setprio(1);                                             \
    _Pragma("unroll")                                                          \
    for (int mf = 0; mf < 2; ++mf)                                             \
      _Pragma("unroll")                                                        \
      for (int ks = 0; ks < 4; ++ks)                                           \
        acc[mf][1] = MFMA32(a01[mf][ks], b1v[ks], acc[mf][1], 0, 0, 0);        \
    __builtin_amdgcn_s_setprio(0);                                             \
    /* P4: stage B1(u+2)->G; vmcnt(6); BAR; refill a01,b0(u+1) from GN; Q11 */ \
    if (u + 2 < NT) {                                                          \
      stage2(pB1, &lds[G][3][0]);                                              \
      asm volatile("s_waitcnt vmcnt(6)" ::: "memory");                         \
    } else {                                                                   \
      asm volatile("s_waitcnt vmcnt(0)" ::: "memory");                         \
    }                                                                          \
    pB1 += BKT;                                                                \
    __builtin_amdgcn_s_barrier();                                              \
    if (u + 1 < NT) {                                                          \
      const short* An = AsB[GN];                                               \
      const short* Bn = BsB[GN];                                               \
      _Pragma("unroll")                                                        \
      for (int mf = 0; mf < 2; ++mf)                                           \
        _Pragma("unroll")                                                      \
        for (int ks = 0; ks < 4; ++ks)                                         \
          a01[mf][ks] = *(const short8*)(An + (mf * 32 + l31) * 64 + gof[ks]); \
      _Pragma("unroll")                                                        \
      for (int ks = 0; ks < 4; ++ks)                                           \
        b0v[ks] = *(const short8*)(Bn + brow0 * 64 + gof[ks]);                 \
    }                                                                          \
    __builtin_amdgcn_s_setprio(1);                                             \
    _Pragma("unroll")                                                          \
    for (int mf = 0; mf < 2; ++mf)                                             \
      _Pragma("unroll")                                                        \
      for (int ks = 0; ks < 4; ++ks)                                           \
        acc[mf + 2][1] = MFMA32(a23[mf][ks], b1v[ks], acc[mf + 2][1], 0, 0, 0);\
    __builtin_amdgcn_s_setprio(0);                                             \
  }

  for (int u = 0; u < NT; u += 2) {
    STEP_BODY(0, 1)
    ++u;
    STEP_BODY(1, 0)
    --u;
  }
#undef STEP_BODY

  // ---- epilogue: out = (G + offset[n]*rowsum[m]) * scale[n] ----
  // C/D layout: col = lane&31, row = (reg&3) + 8*(reg>>2) + 4*hi
  const int orow0 = bm + wr * 128 + 4 * hi;
  const int ocol0 = bn + wc * 64 + l31;
  #pragma unroll
  for (int mf = 0; mf < 4; ++mf) {
    const int base = orow0 + mf * 32;
    float4 rsq[4];
    #pragma unroll
    for (int q = 0; q < 4; ++q)
      rsq[q] = *(const float4*)&rowsum[base + q * 8];
    #pragma unroll
    for (int nf = 0; nf < 2; ++nf) {
      const int n = ocol0 + nf * 32;
      const float sc = scale[n];
      const float of = offset[n];
      #pragma unroll
      for (int q = 0; q < 4; ++q) {
        const int rb = base + q * 8;
        out[(size_t)(rb + 0) * N_DIM + n] = (acc[mf][nf][q * 4 + 0] + of * rsq[q].x) * sc;
        out[(size_t)(rb + 1) * N_DIM + n] = (acc[mf][nf][q * 4 + 1] + of * rsq[q].y) * sc;
        out[(size_t)(rb + 2) * N_DIM + n] = (acc[mf][nf][q * 4 + 2] + of * rsq[q].z) * sc;
        out[(size_t)(rb + 3) * N_DIM + n] = (acc[mf][nf][q * 4 + 3] + of * rsq[q].w) * sc;
      }
    }
  }
}

// ---------------- fallback (ws too small): exact f32 tiled GEMM ----------------
__global__ __launch_bounds__(256) void fallback_gemm(const float* __restrict__ x,
                                                     const int* __restrict__ w,
                                                     const float* __restrict__ scale,
                                                     const float* __restrict__ offset,
                                                     float* __restrict__ out) {
  __shared__ float xs[32][33];
  __shared__ float bs[32][33];
  const int bm = blockIdx.y * 32, bn = blockIdx.x * 32;
  const int t = threadIdx.x;
  const int tm = t >> 5, tn = t & 31;
  float acc[4] = {0.f, 0.f, 0.f, 0.f};
  for (int k0 = 0; k0 < K_DIM; k0 += 32) {
    #pragma unroll
    for (int i = 0; i < 4; ++i) {
      int idx = t + i * 256; int r = idx >> 5, c = idx & 31;
      xs[r][c] = x[(size_t)(bm + r) * K_DIM + k0 + c];
      bs[r][c] = ((float)w[(size_t)(k0 + r) * N_DIM + bn + c] + offset[bn + c]) * scale[bn + c];
    }
    __syncthreads();
    #pragma unroll 8
    for (int kk = 0; kk < 32; ++kk) {
      float wv = bs[kk][tn];
      #pragma unroll
      for (int i = 0; i < 4; ++i) acc[i] += xs[tm + 8 * i][kk] * wv;
    }
    __syncthreads();
  }
  #pragma unroll
  for (int i = 0; i < 4; ++i)
    out[(size_t)(bm + tm + 8 * i) * N_DIM + bn + tn] = acc[i];
}

extern "C" void kernel_launch(void* const* d_in, const int* in_sizes, int n_in,
                              void* d_out, int out_size, void* d_ws, size_t ws_size,
                              hipStream_t stream) {
  const float* x      = (const float*)d_in[0];
  const int*   w      = (const int*)d_in[1];
  const float* scale  = (const float*)d_in[2];
  const float* offset = (const float*)d_in[3];
  float* out = (float*)d_out;

  const size_t xb_bytes = (size_t)M_DIM * K_DIM * 2;
  const size_t wt_bytes = (size_t)N_DIM * K_DIM * 2;
  const size_t rs_bytes = (size_t)M_DIM * 4;

  if (ws_size >= xb_bytes + wt_bytes + rs_bytes) {
    short* xb = (short*)d_ws;
    short* wt = (short*)((char*)d_ws + xb_bytes);
    float* rowsum = (float*)((char*)d_ws + xb_bytes + wt_bytes);
    convert_x_kernel<<<M_DIM, 256, 0, stream>>>(x, xb, rowsum);
    convert_w_kernel<<<dim3(K_DIM / 64, N_DIM / 64), 256, 0, stream>>>(w, wt);
    gemm_kernel<<<GRID_MN, 512, 0, stream>>>(xb, wt, scale, offset, rowsum, out);
  } else {
    fallback_gemm<<<dim3(N_DIM / 32, M_DIM / 32), 256, 0, stream>>>(x, w, scale, offset, out);
  }
}